// Round 7
// baseline (402.920 us; speedup 1.0000x reference)
//
#include <hip/hip_runtime.h>
#include <hip/hip_bf16.h>

// ---------------------------------------------------------------------------
// GCN edge prediction.
//   CSR build (count -> scan -> fill) once per launch.
//   Per layer: LDS-free direct-fragment split-bf16 MFMA GEMM (3-term), epilogue
//              scales rows by dinv -> wave-per-node CSR gather of pre-scaled h'
//              (sum + self, *dv, +bias, [relu]).
//   Decode: 2 label-edges per wave, float4 dot product.
// ---------------------------------------------------------------------------

typedef __attribute__((ext_vector_type(8))) short short8v;   // 8 bf16 = 4 VGPR
typedef __attribute__((ext_vector_type(4))) float f32x4;

__device__ inline unsigned bf16_rne(float f) {
    unsigned u = __float_as_uint(f);
    return (u + 0x7FFF + ((u >> 16) & 1)) >> 16;   // round-to-nearest-even
}

// ---------------- CSR build ----------------

__global__ void count_deg_kernel(const int* __restrict__ dst, int* __restrict__ deg, int E) {
    int e = blockIdx.x * blockDim.x + threadIdx.x;
    if (e < E) atomicAdd(&deg[dst[e]], 1);
}

__global__ __launch_bounds__(1024) void scan1_kernel(int* __restrict__ data,
                                                     int* __restrict__ sums, int n) {
    __shared__ int tmp[1024];
    int t = threadIdx.x;
    int idx = blockIdx.x * 1024 + t;
    int val = (idx < n) ? data[idx] : 0;
    tmp[t] = val;
    __syncthreads();
#pragma unroll
    for (int off = 1; off < 1024; off <<= 1) {
        int v = (t >= off) ? tmp[t - off] : 0;
        __syncthreads();
        tmp[t] += v;
        __syncthreads();
    }
    if (idx < n) data[idx] = tmp[t] - val;
    if (t == 1023) sums[blockIdx.x] = tmp[t];
}

__global__ void scan2_kernel(int* __restrict__ sums, int nb) {
    int lane = threadIdx.x & 63;
    int v = (lane < nb) ? sums[lane] : 0;
    int orig = v;
#pragma unroll
    for (int d = 1; d < 64; d <<= 1) {
        int t2 = __shfl_up(v, d, 64);
        if (lane >= d) v += t2;
    }
    if (lane < nb) sums[lane] = v - orig;
}

__global__ __launch_bounds__(1024) void scan3_kernel(int* __restrict__ data,
                                                     const int* __restrict__ sums, int n) {
    int idx = blockIdx.x * 1024 + threadIdx.x;
    if (idx < n && blockIdx.x > 0) data[idx] += sums[blockIdx.x];
}

__global__ void make_dinv_kernel(const int* __restrict__ off, float* __restrict__ dinv,
                                 int n, int E) {
    int v = blockIdx.x * blockDim.x + threadIdx.x;
    if (v < n) {
        int o1 = (v + 1 < n) ? off[v + 1] : E;
        float d = (float)(o1 - off[v]) + 1.0f;
        dinv[v] = 1.0f / sqrtf(d);
    }
}

__global__ void csr_fill_kernel(const int* __restrict__ src, const int* __restrict__ dst,
                                const int* __restrict__ off, int* __restrict__ fill,
                                int* __restrict__ csr_src, int E) {
    int e = blockIdx.x * blockDim.x + threadIdx.x;
    if (e >= E) return;
    int d = dst[e];
    int pos = atomicAdd(&fill[d], 1);
    csr_src[off[d] + pos] = src[e];
}

// ---------------- W split + transpose ----------------
// W[K][128] fp32 -> Wh/Wl[128][K] bf16 (as short)

__global__ void split_w_kernel(const float* __restrict__ W, short* __restrict__ Wh,
                               short* __restrict__ Wl, int K) {
    int idx = blockIdx.x * blockDim.x + threadIdx.x;
    if (idx >= K * 128) return;
    int k = idx >> 7, col = idx & 127;
    float f = W[idx];
    unsigned h = bf16_rne(f);
    float fh = __uint_as_float(h << 16);
    unsigned l = bf16_rne(f - fh);
    Wh[col * K + k] = (short)h;
    Wl[col * K + k] = (short)l;
}

// ---------------- LDS-free direct-fragment MFMA GEMM ----------------
// out[M][128] = dinv[row] * (A[M][K] @ W[K][128]); Wt as [128][K] bf16 hi/lo.
// BM=64, 256 thr = 4 waves; wave owns 16 exclusive rows x 128 cols.
// A-frags per-lane direct from global (fp32 -> hi/lo inline); B-frags per-lane
// direct from Wt (L1/L2-hot). No LDS, no barriers.

template<int K>
__global__ __launch_bounds__(256) void gemm_mfma_direct(const float* __restrict__ A,
                                                        const short* __restrict__ Wh,
                                                        const short* __restrict__ Wl,
                                                        const float* __restrict__ dinv,
                                                        float* __restrict__ out,
                                                        int M) {
    const int t = threadIdx.x;
    const int lane = t & 63;
    const int w = t >> 6;
    const int row16 = blockIdx.x * 64 + w * 16;        // wave's row base
    const int arow = min(row16 + (lane & 15), M - 1);  // clamped load row
    const int kgrp = (lane >> 4) * 8;                  // k-elem offset in 32-slice
    const int bcol = lane & 15;

    const float* Abase = A + (size_t)arow * K + kgrp;

    f32x4 acc[8];
#pragma unroll
    for (int c = 0; c < 8; ++c) acc[c] = (f32x4){0.f, 0.f, 0.f, 0.f};

#pragma unroll
    for (int kt = 0; kt < K / 64; ++kt) {
        // ---- A fragments for this 64-k step: 2 slices of 32, fp32 -> hi/lo
        short8v ah[2], al[2];
#pragma unroll
        for (int ks = 0; ks < 2; ++ks) {
            const float* ap = Abase + kt * 64 + ks * 32;
            float4 v0 = *reinterpret_cast<const float4*>(ap);
            float4 v1 = *reinterpret_cast<const float4*>(ap + 4);
            float f[8] = {v0.x, v0.y, v0.z, v0.w, v1.x, v1.y, v1.z, v1.w};
#pragma unroll
            for (int j = 0; j < 8; ++j) {
                unsigned h = bf16_rne(f[j]);
                float fh = __uint_as_float(h << 16);
                unsigned l = bf16_rne(f[j] - fh);
                ah[ks][j] = (short)h;
                al[ks][j] = (short)l;
            }
        }
        // ---- per 16-col block: direct B frags + 12 MFMA
#pragma unroll
        for (int c = 0; c < 8; ++c) {
            const short* bh_p = Wh + (size_t)(c * 16 + bcol) * K + kt * 64 + kgrp;
            const short* bl_p = Wl + (size_t)(c * 16 + bcol) * K + kt * 64 + kgrp;
            short8v bh0 = *reinterpret_cast<const short8v*>(bh_p);
            short8v bh1 = *reinterpret_cast<const short8v*>(bh_p + 32);
            short8v bl0 = *reinterpret_cast<const short8v*>(bl_p);
            short8v bl1 = *reinterpret_cast<const short8v*>(bl_p + 32);
            acc[c] = __builtin_amdgcn_mfma_f32_16x16x32_bf16(ah[0], bh0, acc[c], 0, 0, 0);
            acc[c] = __builtin_amdgcn_mfma_f32_16x16x32_bf16(ah[0], bl0, acc[c], 0, 0, 0);
            acc[c] = __builtin_amdgcn_mfma_f32_16x16x32_bf16(al[0], bh0, acc[c], 0, 0, 0);
            acc[c] = __builtin_amdgcn_mfma_f32_16x16x32_bf16(ah[1], bh1, acc[c], 0, 0, 0);
            acc[c] = __builtin_amdgcn_mfma_f32_16x16x32_bf16(ah[1], bl1, acc[c], 0, 0, 0);
            acc[c] = __builtin_amdgcn_mfma_f32_16x16x32_bf16(al[1], bh1, acc[c], 0, 0, 0);
        }
    }

    // ---- epilogue: row-scale by dinv; C/D layout col=lane&15, row=(lane>>4)*4+r
#pragma unroll
    for (int r = 0; r < 4; ++r) {
        int row = row16 + (lane >> 4) * 4 + r;
        if (row < M) {
            float ds = dinv[row];
#pragma unroll
            for (int c = 0; c < 8; ++c)
                out[(size_t)row * 128 + c * 16 + bcol] = acc[c][r] * ds;
        }
    }
}

// ---------------- gather ----------------
// out[v] = relu( dv * (sum_{s in N(v)} h'[s] + h'[v]) + bias ),  h' = dinv*h.

__global__ __launch_bounds__(256) void gather_kernel(const int* __restrict__ off,
                                                     const int* __restrict__ csr_src,
                                                     const float* __restrict__ dinv,
                                                     const float* __restrict__ hp,
                                                     const float* __restrict__ bias,
                                                     float* __restrict__ out,
                                                     int n, int E, int do_relu) {
    int gid = blockIdx.x * blockDim.x + threadIdx.x;
    int v = gid >> 6;
    int lane = gid & 63;
    if (v >= n) return;

    int o0 = off[v];
    int o1 = (v + 1 < n) ? off[v + 1] : E;

    const float2* __restrict__ hp2 = reinterpret_cast<const float2*>(hp);
    float2 sv = hp2[(size_t)v * 64 + lane];          // self row
    float ax = sv.x, ay = sv.y;
    float bx = 0.0f, by = 0.0f;

    for (int base = o0; base < o1; base += 64) {
        int cnt = min(64, o1 - base);
        int myidx = (lane < cnt) ? csr_src[base + lane] : 0;
        int j = 0;
        for (; j + 4 <= cnt; j += 4) {
            int i0 = __shfl(myidx, j,     64);
            int i1 = __shfl(myidx, j + 1, 64);
            int i2 = __shfl(myidx, j + 2, 64);
            int i3 = __shfl(myidx, j + 3, 64);
            float2 h0 = hp2[(size_t)i0 * 64 + lane];
            float2 h1 = hp2[(size_t)i1 * 64 + lane];
            float2 h2 = hp2[(size_t)i2 * 64 + lane];
            float2 h3 = hp2[(size_t)i3 * 64 + lane];
            ax += h0.x; ay += h0.y;
            bx += h1.x; by += h1.y;
            ax += h2.x; ay += h2.y;
            bx += h3.x; by += h3.y;
        }
        for (; j < cnt; ++j) {
            int s = __shfl(myidx, j, 64);
            float2 hv = hp2[(size_t)s * 64 + lane];
            ax += hv.x; ay += hv.y;
        }
    }

    float dv = dinv[v];
    float2 bb = *reinterpret_cast<const float2*>(&bias[lane * 2]);
    float ox = dv * (ax + bx) + bb.x;
    float oy = dv * (ay + by) + bb.y;
    if (do_relu) { ox = fmaxf(ox, 0.0f); oy = fmaxf(oy, 0.0f); }
    *reinterpret_cast<float2*>(&out[(size_t)v * 128 + lane * 2]) = make_float2(ox, oy);
}

// ---------------- decode: 2 edges per wave, float4 per lane ----------------

__global__ __launch_bounds__(256) void decode_kernel(const int* __restrict__ ia,
                                                     const int* __restrict__ ib,
                                                     const float* __restrict__ z,
                                                     float* __restrict__ out, int EL) {
    int gid = blockIdx.x * blockDim.x + threadIdx.x;
    int e = gid >> 5;                 // 32 lanes per edge
    int l5 = gid & 31;
    if (e >= EL) return;
    int a = ia[e], b = ib[e];
    const float4* z4 = reinterpret_cast<const float4*>(z);
    float4 za = z4[(size_t)a * 32 + l5];
    float4 zb = z4[(size_t)b * 32 + l5];
    float s = za.x * zb.x + za.y * zb.y + za.z * zb.z + za.w * zb.w;
#pragma unroll
    for (int off = 16; off > 0; off >>= 1) s += __shfl_down(s, off, 64);
    if (l5 == 0) out[e] = s;
}

// ---------------- host launch ----------------

extern "C" void kernel_launch(void* const* d_in, const int* in_sizes, int n_in,
                              void* d_out, int out_size, void* d_ws, size_t ws_size,
                              hipStream_t stream) {
    const float* x   = (const float*)d_in[0];
    const int*   ei  = (const int*)d_in[1];
    const int*   eli = (const int*)d_in[2];
    const float* W0  = (const float*)d_in[3];
    const float* b0  = (const float*)d_in[4];
    const float* W1  = (const float*)d_in[5];
    const float* b1  = (const float*)d_in[6];
    const float* W2  = (const float*)d_in[7];
    const float* b2  = (const float*)d_in[8];
    float* out = (float*)d_out;

    const int H    = in_sizes[4];            // 128
    const int F_in = in_sizes[3] / H;        // 256
    const int n    = in_sizes[0] / F_in;     // 50000
    const int E    = in_sizes[1] / 2;        // 320000
    const int EL   = in_sizes[2] / 2;        // 200000

    const int* src = ei;
    const int* dst = ei + E;
    const int* la  = eli;
    const int* lb  = eli + EL;

    char* ws = (char*)d_ws;
    size_t p = 0;
    auto alloc = [&](size_t bytes) { char* r = ws + p; p = (p + bytes + 255) & ~(size_t)255; return r; };
    float* dinv    = (float*)alloc((size_t)n * 4);
    int*   off     = (int*)  alloc((size_t)n * 4);
    int*   csr_src = (int*)  alloc((size_t)E * 4);
    int*   sums    = (int*)  alloc(64 * 4);
    short* W0h     = (short*)alloc((size_t)F_in * H * 2);
    short* W0l     = (short*)alloc((size_t)F_in * H * 2);
    short* W1h     = (short*)alloc((size_t)H * H * 2);
    short* W1l     = (short*)alloc((size_t)H * H * 2);
    short* W2h     = (short*)alloc((size_t)H * H * 2);
    short* W2l     = (short*)alloc((size_t)H * H * 2);
    float* bufA    = (float*)alloc((size_t)n * 128 * 4);
    float* bufB    = (float*)alloc((size_t)n * 128 * 4);
    int*   fill    = (int*)bufB;   // alias: only used during CSR build

    const int T = 256;
    dim3 blk(T);

    // ---- CSR build + normalization + weight split
    hipMemsetAsync(off, 0, (size_t)n * 4, stream);
    hipMemsetAsync(fill, 0, (size_t)n * 4, stream);
    split_w_kernel<<<(F_in * H + T - 1) / T, blk, 0, stream>>>(W0, W0h, W0l, F_in);
    split_w_kernel<<<(H * H + T - 1) / T, blk, 0, stream>>>(W1, W1h, W1l, H);
    split_w_kernel<<<(H * H + T - 1) / T, blk, 0, stream>>>(W2, W2h, W2l, H);
    count_deg_kernel<<<(E + T - 1) / T, blk, 0, stream>>>(dst, off, E);
    int nb = (n + 1023) / 1024;
    scan1_kernel<<<nb, 1024, 0, stream>>>(off, sums, n);
    scan2_kernel<<<1, 64, 0, stream>>>(sums, nb);
    scan3_kernel<<<nb, 1024, 0, stream>>>(off, sums, n);
    make_dinv_kernel<<<(n + T - 1) / T, blk, 0, stream>>>(off, dinv, n, E);
    csr_fill_kernel<<<(E + T - 1) / T, blk, 0, stream>>>(src, dst, off, fill, csr_src, E);

    const int mblocks       = (n + 63) / 64;
    const int gather_blocks = (int)(((long long)n * 64 + T - 1) / T);

    // ---- layer 0: x(256) -> 128, relu
    gemm_mfma_direct<256><<<mblocks, blk, 0, stream>>>(x, W0h, W0l, dinv, bufA, n);
    gather_kernel<<<gather_blocks, blk, 0, stream>>>(off, csr_src, dinv, bufA, b0, bufB, n, E, 1);

    // ---- layer 1: 128 -> 128, relu
    gemm_mfma_direct<128><<<mblocks, blk, 0, stream>>>(bufB, W1h, W1l, dinv, bufA, n);
    gather_kernel<<<gather_blocks, blk, 0, stream>>>(off, csr_src, dinv, bufA, b1, bufB, n, E, 1);

    // ---- layer 2: 128 -> 128, no activation
    gemm_mfma_direct<128><<<mblocks, blk, 0, stream>>>(bufB, W2h, W2l, dinv, bufA, n);
    gather_kernel<<<gather_blocks, blk, 0, stream>>>(off, csr_src, dinv, bufA, b2, bufB, n, E, 0);

    // ---- decode
    const int dec_blocks = (int)(((long long)EL * 32 + T - 1) / T);
    decode_kernel<<<dec_blocks, blk, 0, stream>>>(la, lb, bufB, out, EL);
}

// Round 8
// 338.128 us; speedup vs baseline: 1.1916x; 1.1916x over previous
//
#include <hip/hip_runtime.h>
#include <hip/hip_bf16.h>

// ---------------------------------------------------------------------------
// GCN edge prediction.
//   All GEMM operands pre-packed in MFMA-fragment order so every GEMM load is
//   `base + lane*16B` (fully coalesced), no LDS, no barriers, no in-loop cvt.
//   Packed tile layout (16 rows x K): elem(row r, k) at tile_base + (k/8)*128
//   + r*8 + k%8  (shorts). A wave frag (k-slice s of 32) = base + s*512 + lane*8.
//   Per layer: packed-GEMM (split-bf16 3-term) -> CSR gather (writes next
//   layer's packed A directly; last layer writes fp32 rows for decode).
// ---------------------------------------------------------------------------

typedef __attribute__((ext_vector_type(8))) short short8v;   // 8 bf16 = 4 VGPR
typedef __attribute__((ext_vector_type(4))) float f32x4;

__device__ inline unsigned bf16_rne(float f) {
    unsigned u = __float_as_uint(f);
    return (u + 0x7FFF + ((u >> 16) & 1)) >> 16;   // round-to-nearest-even
}

// ---------------- CSR build ----------------

__global__ void count_deg_kernel(const int* __restrict__ dst, int* __restrict__ deg, int E) {
    int e = blockIdx.x * blockDim.x + threadIdx.x;
    if (e < E) atomicAdd(&deg[dst[e]], 1);
}

__global__ __launch_bounds__(1024) void scan1_kernel(int* __restrict__ data,
                                                     int* __restrict__ sums, int n) {
    __shared__ int tmp[1024];
    int t = threadIdx.x;
    int idx = blockIdx.x * 1024 + t;
    int val = (idx < n) ? data[idx] : 0;
    tmp[t] = val;
    __syncthreads();
#pragma unroll
    for (int off = 1; off < 1024; off <<= 1) {
        int v = (t >= off) ? tmp[t - off] : 0;
        __syncthreads();
        tmp[t] += v;
        __syncthreads();
    }
    if (idx < n) data[idx] = tmp[t] - val;
    if (t == 1023) sums[blockIdx.x] = tmp[t];
}

__global__ void scan2_kernel(int* __restrict__ sums, int nb) {
    int lane = threadIdx.x & 63;
    int v = (lane < nb) ? sums[lane] : 0;
    int orig = v;
#pragma unroll
    for (int d = 1; d < 64; d <<= 1) {
        int t2 = __shfl_up(v, d, 64);
        if (lane >= d) v += t2;
    }
    if (lane < nb) sums[lane] = v - orig;
}

__global__ __launch_bounds__(1024) void scan3_kernel(int* __restrict__ data,
                                                     const int* __restrict__ sums, int n) {
    int idx = blockIdx.x * 1024 + threadIdx.x;
    if (idx < n && blockIdx.x > 0) data[idx] += sums[blockIdx.x];
}

__global__ void make_dinv_kernel(const int* __restrict__ off, float* __restrict__ dinv,
                                 int n, int E) {
    int v = blockIdx.x * blockDim.x + threadIdx.x;
    if (v < n) {
        int o1 = (v + 1 < n) ? off[v + 1] : E;
        float d = (float)(o1 - off[v]) + 1.0f;
        dinv[v] = 1.0f / sqrtf(d);
    }
}

__global__ void csr_fill_kernel(const int* __restrict__ src, const int* __restrict__ dst,
                                const int* __restrict__ off, int* __restrict__ fill,
                                int* __restrict__ csr_src, int E) {
    int e = blockIdx.x * blockDim.x + threadIdx.x;
    if (e >= E) return;
    int d = dst[e];
    int pos = atomicAdd(&fill[d], 1);
    csr_src[off[d] + pos] = src[e];
}

// ---------------- W split + pack to fragment order ----------------
// W[K][128] fp32 -> Whp/Wlp packed: col-tile c (16 cols), k-slice s (32),
// block (c*(K/32)+s)*512 shorts; within: (k%32/8)*128 + (col%16)*8 + k%8.

__global__ void split_w_kernel(const float* __restrict__ W, short* __restrict__ Whp,
                               short* __restrict__ Wlp, int K) {
    int idx = blockIdx.x * blockDim.x + threadIdx.x;
    if (idx >= K * 128) return;
    int k = idx >> 7, col = idx & 127;
    float f = W[idx];
    unsigned h = bf16_rne(f);
    float fh = __uint_as_float(h << 16);
    unsigned l = bf16_rne(f - fh);
    int NS = K >> 5;
    int c = col >> 4, col16 = col & 15, s = k >> 5, q = (k >> 3) & 3, j = k & 7;
    int waddr = (c * NS + s) * 512 + q * 128 + col16 * 8 + j;
    Whp[waddr] = (short)h;
    Wlp[waddr] = (short)l;
}

// ---------------- pack x to fragment order (layer-0 A) ----------------
// One thread per 8-elem chunk: gid -> (tile g, chunk c8, row r).
// Reads x[g*16+r][c8*8 .. +8], writes 16B hi + 16B lo coalesced.

template<int K>
__global__ __launch_bounds__(256) void pack_a_kernel(const float* __restrict__ x,
                                                     short* __restrict__ Ahp,
                                                     short* __restrict__ Alp,
                                                     int M, int ntiles) {
    int gid = blockIdx.x * blockDim.x + threadIdx.x;
    const int CH = K / 8;
    if (gid >= ntiles * 16 * CH) return;
    int r  = gid & 15;
    int c8 = (gid >> 4) % CH;
    int g  = gid / (16 * CH);
    int row = g * 16 + r;
    if (row >= M) row = M - 1;                       // clamp (pad tiles)
    const float* xp = x + (size_t)row * K + c8 * 8;
    float4 v0 = *reinterpret_cast<const float4*>(xp);
    float4 v1 = *reinterpret_cast<const float4*>(xp + 4);
    float f[8] = {v0.x, v0.y, v0.z, v0.w, v1.x, v1.y, v1.z, v1.w};
    short8v hv, lv;
#pragma unroll
    for (int j = 0; j < 8; ++j) {
        unsigned h = bf16_rne(f[j]);
        float fh = __uint_as_float(h << 16);
        unsigned l = bf16_rne(f[j] - fh);
        hv[j] = (short)h;
        lv[j] = (short)l;
    }
    size_t waddr = (size_t)g * 16 * K + c8 * 128 + r * 8;
    *reinterpret_cast<short8v*>(&Ahp[waddr]) = hv;
    *reinterpret_cast<short8v*>(&Alp[waddr]) = lv;
}

// ---------------- packed-operand MFMA GEMM ----------------
// out[M][128] = dinv[row] * (A @ W); A,W pre-packed frag-order bf16 hi/lo.
// 256 thr = 4 waves; wave owns one 16-row tile x 128 cols.
// Zero LDS / barriers / conversions; every load = base + lane*16B.

template<int K>
__global__ __launch_bounds__(256) void gemm_mfma_packed(const short* __restrict__ Ahp,
                                                        const short* __restrict__ Alp,
                                                        const short* __restrict__ Whp,
                                                        const short* __restrict__ Wlp,
                                                        const float* __restrict__ dinv,
                                                        float* __restrict__ out,
                                                        int M) {
    constexpr int NS = K / 32;                       // 32-k slices
    const int lane = threadIdx.x & 63;
    const int w = threadIdx.x >> 6;
    const int gtile = blockIdx.x * 4 + w;
    const int row16 = gtile * 16;
    if (row16 >= M) return;                          // padded-wave guard (no barriers)

    const short* ab = Ahp + (size_t)gtile * 16 * K + lane * 8;
    const short* lb = Alp + (size_t)gtile * 16 * K + lane * 8;

    short8v ah[NS], al[NS];
#pragma unroll
    for (int s = 0; s < NS; ++s) {
        ah[s] = *reinterpret_cast<const short8v*>(ab + s * 512);
        al[s] = *reinterpret_cast<const short8v*>(lb + s * 512);
    }

    f32x4 acc[8];
#pragma unroll
    for (int c = 0; c < 8; ++c) acc[c] = (f32x4){0.f, 0.f, 0.f, 0.f};

#pragma unroll
    for (int c = 0; c < 8; ++c) {
        const short* bb = Whp + (size_t)(c * NS) * 512 + lane * 8;
        const short* cb = Wlp + (size_t)(c * NS) * 512 + lane * 8;
#pragma unroll
        for (int s = 0; s < NS; ++s) {
            short8v bh = *reinterpret_cast<const short8v*>(bb + s * 512);
            short8v bl = *reinterpret_cast<const short8v*>(cb + s * 512);
            acc[c] = __builtin_amdgcn_mfma_f32_16x16x32_bf16(ah[s], bh, acc[c], 0, 0, 0);
            acc[c] = __builtin_amdgcn_mfma_f32_16x16x32_bf16(ah[s], bl, acc[c], 0, 0, 0);
            acc[c] = __builtin_amdgcn_mfma_f32_16x16x32_bf16(al[s], bh, acc[c], 0, 0, 0);
        }
    }

    // epilogue: row-scale by dinv; C/D layout col=lane&15, row=(lane>>4)*4+r
#pragma unroll
    for (int r = 0; r < 4; ++r) {
        int row = row16 + (lane >> 4) * 4 + r;
        if (row < M) {
            float ds = dinv[row];
#pragma unroll
            for (int c = 0; c < 8; ++c)
                out[(size_t)row * 128 + c * 16 + (lane & 15)] = acc[c][r] * ds;
        }
    }
}

// ---------------- gather ----------------
// out[v] = relu( dv * (sum_{s in N(v)} h'[s] + h'[v]) + bias ),  h' = dinv*h.
// PACKED=1: write next layer's A in packed hi/lo bf16 (K=128).
// PACKED=0: write fp32 row-major (for decode).

template<int PACKED>
__global__ __launch_bounds__(256) void gather_kernel(const int* __restrict__ off,
                                                     const int* __restrict__ csr_src,
                                                     const float* __restrict__ dinv,
                                                     const float* __restrict__ hp,
                                                     const float* __restrict__ bias,
                                                     float* __restrict__ outf,
                                                     short* __restrict__ Ahp,
                                                     short* __restrict__ Alp,
                                                     int n, int E, int do_relu) {
    int gid = blockIdx.x * blockDim.x + threadIdx.x;
    int v = gid >> 6;
    int lane = gid & 63;
    if (v >= n) return;

    int o0 = off[v];
    int o1 = (v + 1 < n) ? off[v + 1] : E;

    const float2* __restrict__ hp2 = reinterpret_cast<const float2*>(hp);
    float2 sv = hp2[(size_t)v * 64 + lane];          // self row
    float ax = sv.x, ay = sv.y;
    float bx = 0.0f, by = 0.0f;

    for (int base = o0; base < o1; base += 64) {
        int cnt = min(64, o1 - base);
        int myidx = (lane < cnt) ? csr_src[base + lane] : 0;
        int j = 0;
        for (; j + 4 <= cnt; j += 4) {
            int i0 = __shfl(myidx, j,     64);
            int i1 = __shfl(myidx, j + 1, 64);
            int i2 = __shfl(myidx, j + 2, 64);
            int i3 = __shfl(myidx, j + 3, 64);
            float2 h0 = hp2[(size_t)i0 * 64 + lane];
            float2 h1 = hp2[(size_t)i1 * 64 + lane];
            float2 h2 = hp2[(size_t)i2 * 64 + lane];
            float2 h3 = hp2[(size_t)i3 * 64 + lane];
            ax += h0.x; ay += h0.y;
            bx += h1.x; by += h1.y;
            ax += h2.x; ay += h2.y;
            bx += h3.x; by += h3.y;
        }
        for (; j < cnt; ++j) {
            int s = __shfl(myidx, j, 64);
            float2 hv = hp2[(size_t)s * 64 + lane];
            ax += hv.x; ay += hv.y;
        }
    }

    float dv = dinv[v];
    float2 bb = *reinterpret_cast<const float2*>(&bias[lane * 2]);
    float ox = dv * (ax + bx) + bb.x;
    float oy = dv * (ay + by) + bb.y;
    if (do_relu) { ox = fmaxf(ox, 0.0f); oy = fmaxf(oy, 0.0f); }

    if (PACKED) {
        // k0 = 2*lane, k1 = 2*lane+1 of next layer's K=128 A matrix
        unsigned h0 = bf16_rne(ox);
        unsigned l0 = bf16_rne(ox - __uint_as_float(h0 << 16));
        unsigned h1 = bf16_rne(oy);
        unsigned l1 = bf16_rne(oy - __uint_as_float(h1 << 16));
        int g = v >> 4, r = v & 15;
        int c8 = lane >> 2;                  // (2*lane)/8
        int j0 = (2 * lane) & 7;
        size_t a = (size_t)g * 2048 + c8 * 128 + r * 8 + j0;   // 16*128 shorts per tile
        short2 hv = make_short2((short)h0, (short)h1);
        short2 lv = make_short2((short)l0, (short)l1);
        *reinterpret_cast<short2*>(&Ahp[a]) = hv;
        *reinterpret_cast<short2*>(&Alp[a]) = lv;
    } else {
        *reinterpret_cast<float2*>(&outf[(size_t)v * 128 + lane * 2]) = make_float2(ox, oy);
    }
}

// ---------------- decode: 2 edges per wave, float4 per lane ----------------

__global__ __launch_bounds__(256) void decode_kernel(const int* __restrict__ ia,
                                                     const int* __restrict__ ib,
                                                     const float* __restrict__ z,
                                                     float* __restrict__ out, int EL) {
    int gid = blockIdx.x * blockDim.x + threadIdx.x;
    int e = gid >> 5;                 // 32 lanes per edge
    int l5 = gid & 31;
    if (e >= EL) return;
    int a = ia[e], b = ib[e];
    const float4* z4 = reinterpret_cast<const float4*>(z);
    float4 za = z4[(size_t)a * 32 + l5];
    float4 zb = z4[(size_t)b * 32 + l5];
    float s = za.x * zb.x + za.y * zb.y + za.z * zb.z + za.w * zb.w;
#pragma unroll
    for (int off = 16; off > 0; off >>= 1) s += __shfl_down(s, off, 64);
    if (l5 == 0) out[e] = s;
}

// ---------------- host launch ----------------

extern "C" void kernel_launch(void* const* d_in, const int* in_sizes, int n_in,
                              void* d_out, int out_size, void* d_ws, size_t ws_size,
                              hipStream_t stream) {
    const float* x   = (const float*)d_in[0];
    const int*   ei  = (const int*)d_in[1];
    const int*   eli = (const int*)d_in[2];
    const float* W0  = (const float*)d_in[3];
    const float* b0  = (const float*)d_in[4];
    const float* W1  = (const float*)d_in[5];
    const float* b1  = (const float*)d_in[6];
    const float* W2  = (const float*)d_in[7];
    const float* b2  = (const float*)d_in[8];
    float* out = (float*)d_out;

    const int H    = in_sizes[4];            // 128
    const int F_in = in_sizes[3] / H;        // 256
    const int n    = in_sizes[0] / F_in;     // 50000
    const int E    = in_sizes[1] / 2;        // 320000
    const int EL   = in_sizes[2] / 2;        // 200000

    const int* src = ei;
    const int* dst = ei + E;
    const int* la  = eli;
    const int* lb  = eli + EL;

    const int ntiles = (n + 15) / 16;        // 16-row tiles (3125)

    char* ws = (char*)d_ws;
    size_t p = 0;
    auto alloc = [&](size_t bytes) { char* r = ws + p; p = (p + bytes + 255) & ~(size_t)255; return r; };
    float* dinv    = (float*)alloc((size_t)n * 4);
    int*   off     = (int*)  alloc((size_t)n * 4);
    int*   csr_src = (int*)  alloc((size_t)E * 4);
    int*   sums    = (int*)  alloc(64 * 4);
    short* W0h     = (short*)alloc((size_t)F_in * H * 2);
    short* W0l     = (short*)alloc((size_t)F_in * H * 2);
    short* W1h     = (short*)alloc((size_t)H * H * 2);
    short* W1l     = (short*)alloc((size_t)H * H * 2);
    short* W2h     = (short*)alloc((size_t)H * H * 2);
    short* W2l     = (short*)alloc((size_t)H * H * 2);
    short* pkh     = (short*)alloc((size_t)ntiles * 16 * F_in * 2);  // packed A hi (K<=256)
    short* pkl     = (short*)alloc((size_t)ntiles * 16 * F_in * 2);  // packed A lo
    float* bufA    = (float*)alloc((size_t)n * 128 * 4);             // gemm out (fp32 rows)
    float* bufB    = (float*)alloc((size_t)n * 128 * 4);             // final z (fp32 rows)
    int*   fill    = (int*)bufB;   // alias: only used during CSR build

    const int T = 256;
    dim3 blk(T);

    // ---- CSR build + normalization + weight pack + x pack
    hipMemsetAsync(off, 0, (size_t)n * 4, stream);
    hipMemsetAsync(fill, 0, (size_t)n * 4, stream);
    split_w_kernel<<<(F_in * H + T - 1) / T, blk, 0, stream>>>(W0, W0h, W0l, F_in);
    split_w_kernel<<<(H * H + T - 1) / T, blk, 0, stream>>>(W1, W1h, W1l, H);
    split_w_kernel<<<(H * H + T - 1) / T, blk, 0, stream>>>(W2, W2h, W2l, H);
    {
        long long tot = (long long)ntiles * 16 * (F_in / 8);
        pack_a_kernel<256><<<(int)((tot + T - 1) / T), blk, 0, stream>>>(x, pkh, pkl, n, ntiles);
    }
    count_deg_kernel<<<(E + T - 1) / T, blk, 0, stream>>>(dst, off, E);
    int nb = (n + 1023) / 1024;
    scan1_kernel<<<nb, 1024, 0, stream>>>(off, sums, n);
    scan2_kernel<<<1, 64, 0, stream>>>(sums, nb);
    scan3_kernel<<<nb, 1024, 0, stream>>>(off, sums, n);
    make_dinv_kernel<<<(n + T - 1) / T, blk, 0, stream>>>(off, dinv, n, E);
    csr_fill_kernel<<<(E + T - 1) / T, blk, 0, stream>>>(src, dst, off, fill, csr_src, E);

    const int mblocks       = (ntiles + 3) / 4;                       // 4 tiles (waves) per block
    const int gather_blocks = (int)(((long long)n * 64 + T - 1) / T);

    // ---- layer 0: x(256) -> 128, relu; gather writes packed A for layer 1
    gemm_mfma_packed<256><<<mblocks, blk, 0, stream>>>(pkh, pkl, W0h, W0l, dinv, bufA, n);
    gather_kernel<1><<<gather_blocks, blk, 0, stream>>>(off, csr_src, dinv, bufA, b0,
                                                        nullptr, pkh, pkl, n, E, 1);

    // ---- layer 1: 128 -> 128, relu; gather writes packed A for layer 2
    gemm_mfma_packed<128><<<mblocks, blk, 0, stream>>>(pkh, pkl, W1h, W1l, dinv, bufA, n);
    gather_kernel<1><<<gather_blocks, blk, 0, stream>>>(off, csr_src, dinv, bufA, b1,
                                                        nullptr, pkh, pkl, n, E, 1);

    // ---- layer 2: 128 -> 128, no activation; gather writes fp32 z rows
    gemm_mfma_packed<128><<<mblocks, blk, 0, stream>>>(pkh, pkl, W2h, W2l, dinv, bufA, n);
    gather_kernel<0><<<gather_blocks, blk, 0, stream>>>(off, csr_src, dinv, bufA, b2,
                                                        bufB, nullptr, nullptr, n, E, 0);

    // ---- decode
    const int dec_blocks = (int)(((long long)EL * 32 + T - 1) / T);
    decode_kernel<<<dec_blocks, blk, 0, stream>>>(la, lb, bufB, out, EL);
}

// Round 10
// 332.916 us; speedup vs baseline: 1.2103x; 1.0157x over previous
//
#include <hip/hip_runtime.h>
#include <hip/hip_bf16.h>

// ---------------------------------------------------------------------------
// GCN edge prediction.
//   GEMM operands pre-packed in MFMA-fragment order (every GEMM load is
//   base + lane*16B, coalesced; no LDS, no barriers, no in-loop cvt).
//   Packed tile (16 rows x K): elem(r,k) at tile_base + (k/8)*128 + r*8 + k%8.
//   gather: 8 waves/block own 8 consecutive nodes so packed-tile cache lines
//   (rows r..r+7 of a 16B chunk) are written by ONE block (write combining).
// ---------------------------------------------------------------------------

typedef __attribute__((ext_vector_type(8))) short short8v;   // 8 bf16 = 4 VGPR
typedef __attribute__((ext_vector_type(4))) float f32x4;

__device__ inline unsigned bf16_rne(float f) {
    unsigned u = __float_as_uint(f);
    return (u + 0x7FFF + ((u >> 16) & 1)) >> 16;   // round-to-nearest-even
}

// ---------------- CSR build ----------------

__global__ void count_deg_kernel(const int* __restrict__ dst, int* __restrict__ deg, int E) {
    int e = blockIdx.x * blockDim.x + threadIdx.x;
    if (e < E) atomicAdd(&deg[dst[e]], 1);
}

__global__ __launch_bounds__(1024) void scan1_kernel(int* __restrict__ data,
                                                     int* __restrict__ sums, int n) {
    __shared__ int tmp[1024];
    int t = threadIdx.x;
    int idx = blockIdx.x * 1024 + t;
    int val = (idx < n) ? data[idx] : 0;
    tmp[t] = val;
    __syncthreads();
#pragma unroll
    for (int off = 1; off < 1024; off <<= 1) {
        int v = (t >= off) ? tmp[t - off] : 0;
        __syncthreads();
        tmp[t] += v;
        __syncthreads();
    }
    if (idx < n) data[idx] = tmp[t] - val;
    if (t == 1023) sums[blockIdx.x] = tmp[t];
}

__global__ void scan2_kernel(int* __restrict__ sums, int nb) {
    int lane = threadIdx.x & 63;
    int v = (lane < nb) ? sums[lane] : 0;
    int orig = v;
#pragma unroll
    for (int d = 1; d < 64; d <<= 1) {
        int t2 = __shfl_up(v, d, 64);
        if (lane >= d) v += t2;
    }
    if (lane < nb) sums[lane] = v - orig;
}

__global__ __launch_bounds__(1024) void scan3_kernel(int* __restrict__ data,
                                                     const int* __restrict__ sums, int n) {
    int idx = blockIdx.x * 1024 + threadIdx.x;
    if (idx < n && blockIdx.x > 0) data[idx] += sums[blockIdx.x];
}

__global__ void make_dinv_kernel(const int* __restrict__ off, float* __restrict__ dinv,
                                 int n, int E) {
    int v = blockIdx.x * blockDim.x + threadIdx.x;
    if (v < n) {
        int o1 = (v + 1 < n) ? off[v + 1] : E;
        float d = (float)(o1 - off[v]) + 1.0f;
        dinv[v] = 1.0f / sqrtf(d);
    }
}

__global__ void csr_fill_kernel(const int* __restrict__ src, const int* __restrict__ dst,
                                const int* __restrict__ off, int* __restrict__ fill,
                                int* __restrict__ csr_src, int E) {
    int e = blockIdx.x * blockDim.x + threadIdx.x;
    if (e >= E) return;
    int d = dst[e];
    int pos = atomicAdd(&fill[d], 1);
    csr_src[off[d] + pos] = src[e];
}

// ---------------- all-W split + pack to fragment order (one launch) ----------
// W[K][128] fp32 -> packed: col-tile c (16 cols), k-slice s (32 k), block
// (c*(K/32)+s)*512 shorts; within: ((k%32)/8)*128 + (col%16)*8 + k%8.

__device__ inline void split_pack_one(const float* W, short* Whp, short* Wlp,
                                      int idx, int K) {
    int k = idx >> 7, col = idx & 127;
    float f = W[idx];
    unsigned h = bf16_rne(f);
    float fh = __uint_as_float(h << 16);
    unsigned l = bf16_rne(f - fh);
    int NS = K >> 5;
    int c = col >> 4, col16 = col & 15, s = k >> 5, q = (k >> 3) & 3, j = k & 7;
    int waddr = (c * NS + s) * 512 + q * 128 + col16 * 8 + j;
    Whp[waddr] = (short)h;
    Wlp[waddr] = (short)l;
}

__global__ void split_w_all_kernel(const float* __restrict__ W0, short* __restrict__ W0h,
                                   short* __restrict__ W0l,
                                   const float* __restrict__ W1, short* __restrict__ W1h,
                                   short* __restrict__ W1l,
                                   const float* __restrict__ W2, short* __restrict__ W2h,
                                   short* __restrict__ W2l,
                                   int n0, int n12, int K0, int K12) {
    int idx = blockIdx.x * blockDim.x + threadIdx.x;
    if (idx < n0) { split_pack_one(W0, W0h, W0l, idx, K0); return; }
    idx -= n0;
    if (idx < n12) { split_pack_one(W1, W1h, W1l, idx, K12); return; }
    idx -= n12;
    if (idx < n12) { split_pack_one(W2, W2h, W2l, idx, K12); }
}

// ---------------- pack x to fragment order (layer-0 A) ----------------

template<int K>
__global__ __launch_bounds__(256) void pack_a_kernel(const float* __restrict__ x,
                                                     short* __restrict__ Ahp,
                                                     short* __restrict__ Alp,
                                                     int M, int ntiles) {
    int gid = blockIdx.x * blockDim.x + threadIdx.x;
    const int CH = K / 8;
    if (gid >= ntiles * 16 * CH) return;
    int r  = gid & 15;
    int c8 = (gid >> 4) % CH;
    int g  = gid / (16 * CH);
    int row = g * 16 + r;
    if (row >= M) row = M - 1;                       // clamp (pad tiles)
    const float* xp = x + (size_t)row * K + c8 * 8;
    float4 v0 = *reinterpret_cast<const float4*>(xp);
    float4 v1 = *reinterpret_cast<const float4*>(xp + 4);
    float f[8] = {v0.x, v0.y, v0.z, v0.w, v1.x, v1.y, v1.z, v1.w};
    short8v hv, lv;
#pragma unroll
    for (int j = 0; j < 8; ++j) {
        unsigned h = bf16_rne(f[j]);
        float fh = __uint_as_float(h << 16);
        unsigned l = bf16_rne(f[j] - fh);
        hv[j] = (short)h;
        lv[j] = (short)l;
    }
    size_t waddr = (size_t)g * 16 * K + c8 * 128 + r * 8;
    *reinterpret_cast<short8v*>(&Ahp[waddr]) = hv;
    *reinterpret_cast<short8v*>(&Alp[waddr]) = lv;
}

// ---------------- packed-operand MFMA GEMM ----------------
// out[M][128] = dinv[row] * (A @ W); A,W pre-packed frag-order bf16 hi/lo.
// 256 thr = 4 waves; wave owns one 16-row tile x 128 cols.

template<int K>
__global__ __launch_bounds__(256) void gemm_mfma_packed(const short* __restrict__ Ahp,
                                                        const short* __restrict__ Alp,
                                                        const short* __restrict__ Whp,
                                                        const short* __restrict__ Wlp,
                                                        const float* __restrict__ dinv,
                                                        float* __restrict__ out,
                                                        int M) {
    constexpr int NS = K / 32;                       // 32-k slices
    const int lane = threadIdx.x & 63;
    const int w = threadIdx.x >> 6;
    const int gtile = blockIdx.x * 4 + w;
    const int row16 = gtile * 16;
    if (row16 >= M) return;                          // padded-wave guard (no barriers)

    const short* ab = Ahp + (size_t)gtile * 16 * K + lane * 8;
    const short* lb = Alp + (size_t)gtile * 16 * K + lane * 8;

    short8v ah[NS], al[NS];
#pragma unroll
    for (int s = 0; s < NS; ++s) {
        ah[s] = *reinterpret_cast<const short8v*>(ab + s * 512);
        al[s] = *reinterpret_cast<const short8v*>(lb + s * 512);
    }

    f32x4 acc[8];
#pragma unroll
    for (int c = 0; c < 8; ++c) acc[c] = (f32x4){0.f, 0.f, 0.f, 0.f};

#pragma unroll
    for (int c = 0; c < 8; ++c) {
        const short* bb = Whp + (size_t)(c * NS) * 512 + lane * 8;
        const short* cb = Wlp + (size_t)(c * NS) * 512 + lane * 8;
#pragma unroll
        for (int s = 0; s < NS; ++s) {
            short8v bh = *reinterpret_cast<const short8v*>(bb + s * 512);
            short8v bl = *reinterpret_cast<const short8v*>(cb + s * 512);
            acc[c] = __builtin_amdgcn_mfma_f32_16x16x32_bf16(ah[s], bh, acc[c], 0, 0, 0);
            acc[c] = __builtin_amdgcn_mfma_f32_16x16x32_bf16(ah[s], bl, acc[c], 0, 0, 0);
            acc[c] = __builtin_amdgcn_mfma_f32_16x16x32_bf16(al[s], bh, acc[c], 0, 0, 0);
        }
    }

    // epilogue: row-scale by dinv; C/D layout col=lane&15, row=(lane>>4)*4+r
#pragma unroll
    for (int r = 0; r < 4; ++r) {
        int row = row16 + (lane >> 4) * 4 + r;
        if (row < M) {
            float ds = dinv[row];
#pragma unroll
            for (int c = 0; c < 8; ++c)
                out[(size_t)row * 128 + c * 16 + (lane & 15)] = acc[c][r] * ds;
        }
    }
}

// ---------------- gather ----------------
// out[v] = relu( dv * (sum_{s in N(v)} h'[s] + h'[v]) + bias ),  h' = dinv*h.
// 512 threads = 8 waves = 8 CONSECUTIVE nodes, so each 128B line of the packed
// tile (rows r..r+7 of one 16B chunk) is written by one block.
// PACKED=1: write next layer's packed hi/lo A (K=128). PACKED=0: fp32 rows.

template<int PACKED>
__global__ __launch_bounds__(512) void gather_kernel(const int* __restrict__ off,
                                                     const int* __restrict__ csr_src,
                                                     const float* __restrict__ dinv,
                                                     const float* __restrict__ hp,
                                                     const float* __restrict__ bias,
                                                     float* __restrict__ outf,
                                                     short* __restrict__ Ahp,
                                                     short* __restrict__ Alp,
                                                     int n, int E, int do_relu) {
    int v = blockIdx.x * 8 + (threadIdx.x >> 6);
    int lane = threadIdx.x & 63;
    if (v >= n) return;

    int o0 = off[v];
    int o1 = (v + 1 < n) ? off[v + 1] : E;

    const float2* __restrict__ hp2 = reinterpret_cast<const float2*>(hp);
    float2 sv = hp2[(size_t)v * 64 + lane];          // self row
    float ax = sv.x, ay = sv.y;
    float bx = 0.0f, by = 0.0f;

    for (int base = o0; base < o1; base += 64) {
        int cnt = min(64, o1 - base);
        int myidx = (lane < cnt) ? csr_src[base + lane] : 0;
        int j = 0;
        for (; j + 8 <= cnt; j += 8) {
            int i0 = __shfl(myidx, j,     64);
            int i1 = __shfl(myidx, j + 1, 64);
            int i2 = __shfl(myidx, j + 2, 64);
            int i3 = __shfl(myidx, j + 3, 64);
            int i4 = __shfl(myidx, j + 4, 64);
            int i5 = __shfl(myidx, j + 5, 64);
            int i6 = __shfl(myidx, j + 6, 64);
            int i7 = __shfl(myidx, j + 7, 64);
            float2 h0 = hp2[(size_t)i0 * 64 + lane];
            float2 h1 = hp2[(size_t)i1 * 64 + lane];
            float2 h2 = hp2[(size_t)i2 * 64 + lane];
            float2 h3 = hp2[(size_t)i3 * 64 + lane];
            float2 h4 = hp2[(size_t)i4 * 64 + lane];
            float2 h5 = hp2[(size_t)i5 * 64 + lane];
            float2 h6 = hp2[(size_t)i6 * 64 + lane];
            float2 h7 = hp2[(size_t)i7 * 64 + lane];
            ax += h0.x; ay += h0.y;  bx += h1.x; by += h1.y;
            ax += h2.x; ay += h2.y;  bx += h3.x; by += h3.y;
            ax += h4.x; ay += h4.y;  bx += h5.x; by += h5.y;
            ax += h6.x; ay += h6.y;  bx += h7.x; by += h7.y;
        }
        for (; j + 4 <= cnt; j += 4) {
            int i0 = __shfl(myidx, j,     64);
            int i1 = __shfl(myidx, j + 1, 64);
            int i2 = __shfl(myidx, j + 2, 64);
            int i3 = __shfl(myidx, j + 3, 64);
            float2 h0 = hp2[(size_t)i0 * 64 + lane];
            float2 h1 = hp2[(size_t)i1 * 64 + lane];
            float2 h2 = hp2[(size_t)i2 * 64 + lane];
            float2 h3 = hp2[(size_t)i3 * 64 + lane];
            ax += h0.x; ay += h0.y;  bx += h1.x; by += h1.y;
            ax += h2.x; ay += h2.y;  bx += h3.x; by += h3.y;
        }
        for (; j < cnt; ++j) {
            int s = __shfl(myidx, j, 64);
            float2 hv = hp2[(size_t)s * 64 + lane];
            ax += hv.x; ay += hv.y;
        }
    }

    float dv = dinv[v];
    float2 bb = *reinterpret_cast<const float2*>(&bias[lane * 2]);
    float ox = dv * (ax + bx) + bb.x;
    float oy = dv * (ay + by) + bb.y;
    if (do_relu) { ox = fmaxf(ox, 0.0f); oy = fmaxf(oy, 0.0f); }

    if (PACKED) {
        // k0 = 2*lane, k1 = 2*lane+1 of next layer's K=128 packed A
        unsigned h0 = bf16_rne(ox);
        unsigned l0 = bf16_rne(ox - __uint_as_float(h0 << 16));
        unsigned h1 = bf16_rne(oy);
        unsigned l1 = bf16_rne(oy - __uint_as_float(h1 << 16));
        int g = v >> 4, r = v & 15;
        int c8 = lane >> 2;
        int j0 = (2 * lane) & 7;
        size_t a = (size_t)g * 2048 + c8 * 128 + r * 8 + j0;
        *reinterpret_cast<short2*>(&Ahp[a]) = make_short2((short)h0, (short)h1);
        *reinterpret_cast<short2*>(&Alp[a]) = make_short2((short)l0, (short)l1);
    } else {
        *reinterpret_cast<float2*>(&outf[(size_t)v * 128 + lane * 2]) = make_float2(ox, oy);
    }
}

// ---------------- decode: 32 lanes per edge, float4 per lane ----------------

__global__ __launch_bounds__(256) void decode_kernel(const int* __restrict__ ia,
                                                     const int* __restrict__ ib,
                                                     const float* __restrict__ z,
                                                     float* __restrict__ out, int EL) {
    int gid = blockIdx.x * blockDim.x + threadIdx.x;
    int e = gid >> 5;
    int l5 = gid & 31;
    if (e >= EL) return;
    int a = ia[e], b = ib[e];
    const float4* z4 = reinterpret_cast<const float4*>(z);
    float4 za = z4[(size_t)a * 32 + l5];
    float4 zb = z4[(size_t)b * 32 + l5];
    float s = za.x * zb.x + za.y * zb.y + za.z * zb.z + za.w * zb.w;
#pragma unroll
    for (int off = 16; off > 0; off >>= 1) s += __shfl_down(s, off, 64);
    if (l5 == 0) out[e] = s;
}

// ---------------- host launch ----------------

extern "C" void kernel_launch(void* const* d_in, const int* in_sizes, int n_in,
                              void* d_out, int out_size, void* d_ws, size_t ws_size,
                              hipStream_t stream) {
    const float* x   = (const float*)d_in[0];
    const int*   ei  = (const int*)d_in[1];
    const int*   eli = (const int*)d_in[2];
    const float* W0  = (const float*)d_in[3];
    const float* b0  = (const float*)d_in[4];
    const float* W1  = (const float*)d_in[5];
    const float* b1  = (const float*)d_in[6];
    const float* W2  = (const float*)d_in[7];
    const float* b2  = (const float*)d_in[8];
    float* out = (float*)d_out;

    const int H    = in_sizes[4];            // 128
    const int F_in = in_sizes[3] / H;        // 256
    const int n    = in_sizes[0] / F_in;     // 50000
    const int E    = in_sizes[1] / 2;        // 320000
    const int EL   = in_sizes[2] / 2;        // 200000

    const int* src = ei;
    const int* dst = ei + E;
    const int* la  = eli;
    const int* lb  = eli + EL;

    const int ntiles = (n + 15) / 16;

    char* ws = (char*)d_ws;
    size_t p = 0;
    auto alloc = [&](size_t bytes) { char* r = ws + p; p = (p + bytes + 255) & ~(size_t)255; return r; };
    float* dinv    = (float*)alloc((size_t)n * 4);
    int*   off     = (int*)  alloc((size_t)n * 4);
    int*   csr_src = (int*)  alloc((size_t)E * 4);
    int*   sums    = (int*)  alloc(64 * 4);
    short* W0h     = (short*)alloc((size_t)F_in * H * 2);
    short* W0l     = (short*)alloc((size_t)F_in * H * 2);
    short* W1h     = (short*)alloc((size_t)H * H * 2);
    short* W1l     = (short*)alloc((size_t)H * H * 2);
    short* W2h     = (short*)alloc((size_t)H * H * 2);
    short* W2l     = (short*)alloc((size_t)H * H * 2);
    short* pkh     = (short*)alloc((size_t)ntiles * 16 * F_in * 2);
    short* pkl     = (short*)alloc((size_t)ntiles * 16 * F_in * 2);
    float* bufA    = (float*)alloc((size_t)n * 128 * 4);
    float* bufB    = (float*)alloc((size_t)n * 128 * 4);
    int*   fill    = (int*)bufB;   // alias: only used during CSR build

    const int T = 256;
    dim3 blk(T);

    // ---- CSR build + normalization + weight pack + x pack
    hipMemsetAsync(off, 0, (size_t)n * 4, stream);
    hipMemsetAsync(fill, 0, (size_t)n * 4, stream);
    {
        int n0 = F_in * H, n12 = H * H;
        int tot = n0 + 2 * n12;
        split_w_all_kernel<<<(tot + T - 1) / T, blk, 0, stream>>>(
            W0, W0h, W0l, W1, W1h, W1l, W2, W2h, W2l, n0, n12, F_in, H);
    }
    {
        long long tot = (long long)ntiles * 16 * (F_in / 8);
        pack_a_kernel<256><<<(int)((tot + T - 1) / T), blk, 0, stream>>>(x, pkh, pkl, n, ntiles);
    }
    count_deg_kernel<<<(E + T - 1) / T, blk, 0, stream>>>(dst, off, E);
    int nb = (n + 1023) / 1024;
    scan1_kernel<<<nb, 1024, 0, stream>>>(off, sums, n);
    scan2_kernel<<<1, 64, 0, stream>>>(sums, nb);
    scan3_kernel<<<nb, 1024, 0, stream>>>(off, sums, n);
    make_dinv_kernel<<<(n + T - 1) / T, blk, 0, stream>>>(off, dinv, n, E);
    csr_fill_kernel<<<(E + T - 1) / T, blk, 0, stream>>>(src, dst, off, fill, csr_src, E);

    const int mblocks       = (ntiles + 3) / 4;
    const int gather_blocks = (n + 7) / 8;           // 8 nodes (waves) per block

    // ---- layer 0: x(256) -> 128, relu; gather writes packed A for layer 1
    gemm_mfma_packed<256><<<mblocks, blk, 0, stream>>>(pkh, pkl, W0h, W0l, dinv, bufA, n);
    gather_kernel<1><<<gather_blocks, 512, 0, stream>>>(off, csr_src, dinv, bufA, b0,
                                                        nullptr, pkh, pkl, n, E, 1);

    // ---- layer 1: 128 -> 128, relu; gather writes packed A for layer 2
    gemm_mfma_packed<128><<<mblocks, blk, 0, stream>>>(pkh, pkl, W1h, W1l, dinv, bufA, n);
    gather_kernel<1><<<gather_blocks, 512, 0, stream>>>(off, csr_src, dinv, bufA, b1,
                                                        nullptr, pkh, pkl, n, E, 1);

    // ---- layer 2: 128 -> 128, no activation; gather writes fp32 z rows
    gemm_mfma_packed<128><<<mblocks, blk, 0, stream>>>(pkh, pkl, W2h, W2l, dinv, bufA, n);
    gather_kernel<0><<<gather_blocks, 512, 0, stream>>>(off, csr_src, dinv, bufA, b2,
                                                        bufB, nullptr, nullptr, n, E, 0);

    // ---- decode
    const int dec_blocks = (int)(((long long)EL * 32 + T - 1) / T);
    decode_kernel<<<dec_blocks, blk, 0, stream>>>(la, lb, bufB, out, EL);
}

// Round 12
// 331.784 us; speedup vs baseline: 1.2144x; 1.0034x over previous
//
#include <hip/hip_runtime.h>
#include <hip/hip_bf16.h>

// ---------------------------------------------------------------------------
// GCN edge prediction.
//   GEMM operands pre-packed in MFMA fragment order. Packed A tile = 16 rows:
//   hi half [16*K shorts] then lo half, elem(r,k) at (k/8)*128 + r*8 + k%8.
//   Gather: 1024-thr block = 16 waves = 16 consecutive nodes = exactly ONE
//   packed tile -> all cache lines fully written by one block (no RMW).
//   GEMM: 2 waves per tile (4 col-blocks each) for 2x wave TLP.
// ---------------------------------------------------------------------------

typedef __attribute__((ext_vector_type(8))) short short8v;   // 8 bf16 = 4 VGPR
typedef __attribute__((ext_vector_type(4))) float f32x4;

__device__ inline unsigned bf16_rne(float f) {
    unsigned u = __float_as_uint(f);
    return (u + 0x7FFF + ((u >> 16) & 1)) >> 16;   // round-to-nearest-even
}

// ---------------- fused preamble: zero CSR arrays + split W + pack x ---------
// W layout: (c*NS+s)*512 + q*128 + col16*8 + j  (NS = K/32), separate hi/lo.
// A layout: tile g: g*(16*K*2) + c8*128 + r*8 + j, hi; lo at +16*K (interleaved).

__device__ inline void split_pack_one(const float* W, short* Whp, short* Wlp,
                                      int idx, int K) {
    int k = idx >> 7, col = idx & 127;
    float f = W[idx];
    unsigned h = bf16_rne(f);
    float fh = __uint_as_float(h << 16);
    unsigned l = bf16_rne(f - fh);
    int NS = K >> 5;
    int c = col >> 4, col16 = col & 15, s = k >> 5, q = (k >> 3) & 3, j = k & 7;
    int waddr = (c * NS + s) * 512 + q * 128 + col16 * 8 + j;
    Whp[waddr] = (short)h;
    Wlp[waddr] = (short)l;
}

__global__ __launch_bounds__(256) void preamble_kernel(
        const float* __restrict__ W0, short* __restrict__ W0h, short* __restrict__ W0l,
        const float* __restrict__ W1, short* __restrict__ W1h, short* __restrict__ W1l,
        const float* __restrict__ W2, short* __restrict__ W2h, short* __restrict__ W2l,
        const float* __restrict__ x, short* __restrict__ Axp,
        int* __restrict__ off, int* __restrict__ fill,
        int n, int F_in, int H, int ntiles, int total) {
    int gid = blockIdx.x * blockDim.x + threadIdx.x;
    if (gid >= total) return;
    int idx = gid;
    if (idx < n) { off[idx] = 0; fill[idx] = 0; return; }
    idx -= n;
    int n0 = F_in * H, n12 = H * H;
    if (idx < n0) { split_pack_one(W0, W0h, W0l, idx, F_in); return; }
    idx -= n0;
    if (idx < n12) { split_pack_one(W1, W1h, W1l, idx, H); return; }
    idx -= n12;
    if (idx < n12) { split_pack_one(W2, W2h, W2l, idx, H); return; }
    idx -= n12;
    // pack x: K = F_in; idx in [0, ntiles*16*(F_in/8))
    const int K = F_in;
    const int CH = K / 8;
    int r  = idx & 15;
    int c8 = (idx >> 4) % CH;
    int g  = idx / (16 * CH);
    int row = g * 16 + r;
    if (row >= n) row = n - 1;                      // clamp (pad tiles)
    const float* xp = x + (size_t)row * K + c8 * 8;
    float4 v0 = *reinterpret_cast<const float4*>(xp);
    float4 v1 = *reinterpret_cast<const float4*>(xp + 4);
    float f[8] = {v0.x, v0.y, v0.z, v0.w, v1.x, v1.y, v1.z, v1.w};
    short8v hv, lv;
#pragma unroll
    for (int j = 0; j < 8; ++j) {
        unsigned h = bf16_rne(f[j]);
        float fh = __uint_as_float(h << 16);
        unsigned l = bf16_rne(f[j] - fh);
        hv[j] = (short)h;
        lv[j] = (short)l;
    }
    size_t base = (size_t)g * (16 * K * 2) + c8 * 128 + r * 8;
    *reinterpret_cast<short8v*>(&Axp[base]) = hv;
    *reinterpret_cast<short8v*>(&Axp[base + 16 * K]) = lv;
}

// ---------------- CSR build ----------------

__global__ void count_deg_kernel(const int* __restrict__ dst, int* __restrict__ deg, int E) {
    int e = blockIdx.x * blockDim.x + threadIdx.x;
    if (e < E) atomicAdd(&deg[dst[e]], 1);
}

__global__ __launch_bounds__(1024) void scan1_kernel(int* __restrict__ data,
                                                     int* __restrict__ sums, int n) {
    __shared__ int tmp[1024];
    int t = threadIdx.x;
    int idx = blockIdx.x * 1024 + t;
    int val = (idx < n) ? data[idx] : 0;
    tmp[t] = val;
    __syncthreads();
#pragma unroll
    for (int off = 1; off < 1024; off <<= 1) {
        int v = (t >= off) ? tmp[t - off] : 0;
        __syncthreads();
        tmp[t] += v;
        __syncthreads();
    }
    if (idx < n) data[idx] = tmp[t] - val;
    if (t == 1023) sums[blockIdx.x] = tmp[t];
}

__global__ void scan2_kernel(int* __restrict__ sums, int nb) {
    int lane = threadIdx.x & 63;
    int v = (lane < nb) ? sums[lane] : 0;
    int orig = v;
#pragma unroll
    for (int d = 1; d < 64; d <<= 1) {
        int t2 = __shfl_up(v, d, 64);
        if (lane >= d) v += t2;
    }
    if (lane < nb) sums[lane] = v - orig;
}

__global__ __launch_bounds__(1024) void scan3_kernel(int* __restrict__ data,
                                                     const int* __restrict__ sums, int n) {
    int idx = blockIdx.x * 1024 + threadIdx.x;
    if (idx < n && blockIdx.x > 0) data[idx] += sums[blockIdx.x];
}

__global__ void make_dinv_kernel(const int* __restrict__ off, float* __restrict__ dinv,
                                 int n, int E) {
    int v = blockIdx.x * blockDim.x + threadIdx.x;
    if (v < n) {
        int o1 = (v + 1 < n) ? off[v + 1] : E;
        float d = (float)(o1 - off[v]) + 1.0f;
        dinv[v] = 1.0f / sqrtf(d);
    }
}

__global__ void csr_fill_kernel(const int* __restrict__ src, const int* __restrict__ dst,
                                const int* __restrict__ off, int* __restrict__ fill,
                                int* __restrict__ csr_src, int E) {
    int e = blockIdx.x * blockDim.x + threadIdx.x;
    if (e >= E) return;
    int d = dst[e];
    int pos = atomicAdd(&fill[d], 1);
    csr_src[off[d] + pos] = src[e];
}

// ---------------- packed-operand MFMA GEMM ----------------
// out[M][128] = dinv[row]*(A @ W). 256 thr = 4 waves; 2 waves per 16-row tile,
// each wave owns 4 of 8 col-blocks. Every load = base + lane*16B.

template<int K>
__global__ __launch_bounds__(256) void gemm_mfma_packed(const short* __restrict__ Axp,
                                                        const short* __restrict__ Whp,
                                                        const short* __restrict__ Wlp,
                                                        const float* __restrict__ dinv,
                                                        float* __restrict__ out,
                                                        int M) {
    constexpr int NS = K / 32;
    constexpr size_t TILE = (size_t)16 * K * 2;      // shorts per packed tile
    const int lane = threadIdx.x & 63;
    const int w = threadIdx.x >> 6;
    const int gtile = blockIdx.x * 2 + (w >> 1);
    const int chalf = (w & 1) * 4;
    const int row16 = gtile * 16;
    if (row16 >= M) return;                          // no barriers -> safe

    const short* ab = Axp + (size_t)gtile * TILE + lane * 8;
    const short* lb = ab + 16 * K;

    short8v ah[NS], al[NS];
#pragma unroll
    for (int s = 0; s < NS; ++s) {
        ah[s] = *reinterpret_cast<const short8v*>(ab + s * 512);
        al[s] = *reinterpret_cast<const short8v*>(lb + s * 512);
    }

    f32x4 acc[4];
#pragma unroll
    for (int c = 0; c < 4; ++c) acc[c] = (f32x4){0.f, 0.f, 0.f, 0.f};

#pragma unroll
    for (int c4 = 0; c4 < 4; ++c4) {
        int c = chalf + c4;
        const short* bb = Whp + (size_t)(c * NS) * 512 + lane * 8;
        const short* cb = Wlp + (size_t)(c * NS) * 512 + lane * 8;
#pragma unroll
        for (int s = 0; s < NS; ++s) {
            short8v bh = *reinterpret_cast<const short8v*>(bb + s * 512);
            short8v bl = *reinterpret_cast<const short8v*>(cb + s * 512);
            acc[c4] = __builtin_amdgcn_mfma_f32_16x16x32_bf16(ah[s], bh, acc[c4], 0, 0, 0);
            acc[c4] = __builtin_amdgcn_mfma_f32_16x16x32_bf16(ah[s], bl, acc[c4], 0, 0, 0);
            acc[c4] = __builtin_amdgcn_mfma_f32_16x16x32_bf16(al[s], bh, acc[c4], 0, 0, 0);
        }
    }

    // epilogue: row-scale by dinv; C/D layout col=lane&15, row=(lane>>4)*4+r
#pragma unroll
    for (int r = 0; r < 4; ++r) {
        int row = row16 + (lane >> 4) * 4 + r;
        if (row < M) {
            float ds = dinv[row];
#pragma unroll
            for (int c4 = 0; c4 < 4; ++c4)
                out[(size_t)row * 128 + (chalf + c4) * 16 + (lane & 15)] = acc[c4][r] * ds;
        }
    }
}

// ---------------- gather ----------------
// out[v] = relu( dv*(sum_{s in N(v)} h'[s] + h'[v]) + bias ), h' = dinv*h.
// 1024 threads = 16 waves = nodes blockIdx*16 .. +15 = exactly one packed tile.
// PACKED=1: write interleaved hi/lo packed A (K=128). PACKED=0: fp32 rows.

template<int PACKED>
__global__ __launch_bounds__(1024) void gather_kernel(const int* __restrict__ off,
                                                      const int* __restrict__ csr_src,
                                                      const float* __restrict__ dinv,
                                                      const float* __restrict__ hp,
                                                      const float* __restrict__ bias,
                                                      float* __restrict__ outf,
                                                      short* __restrict__ Axp,
                                                      int n, int E, int do_relu) {
    int v = blockIdx.x * 16 + (threadIdx.x >> 6);
    int lane = threadIdx.x & 63;
    if (v >= n) return;

    int o0 = off[v];
    int o1 = (v + 1 < n) ? off[v + 1] : E;

    const float2* __restrict__ hp2 = reinterpret_cast<const float2*>(hp);
    float2 sv = hp2[(size_t)v * 64 + lane];          // self row
    float ax = sv.x, ay = sv.y;
    float bx = 0.0f, by = 0.0f;

    for (int base = o0; base < o1; base += 64) {
        int cnt = min(64, o1 - base);
        int myidx = (lane < cnt) ? csr_src[base + lane] : 0;
        int j = 0;
        for (; j + 8 <= cnt; j += 8) {
            int i0 = __shfl(myidx, j,     64);
            int i1 = __shfl(myidx, j + 1, 64);
            int i2 = __shfl(myidx, j + 2, 64);
            int i3 = __shfl(myidx, j + 3, 64);
            int i4 = __shfl(myidx, j + 4, 64);
            int i5 = __shfl(myidx, j + 5, 64);
            int i6 = __shfl(myidx, j + 6, 64);
            int i7 = __shfl(myidx, j + 7, 64);
            float2 h0 = hp2[(size_t)i0 * 64 + lane];
            float2 h1 = hp2[(size_t)i1 * 64 + lane];
            float2 h2 = hp2[(size_t)i2 * 64 + lane];
            float2 h3 = hp2[(size_t)i3 * 64 + lane];
            float2 h4 = hp2[(size_t)i4 * 64 + lane];
            float2 h5 = hp2[(size_t)i5 * 64 + lane];
            float2 h6 = hp2[(size_t)i6 * 64 + lane];
            float2 h7 = hp2[(size_t)i7 * 64 + lane];
            ax += h0.x; ay += h0.y;  bx += h1.x; by += h1.y;
            ax += h2.x; ay += h2.y;  bx += h3.x; by += h3.y;
            ax += h4.x; ay += h4.y;  bx += h5.x; by += h5.y;
            ax += h6.x; ay += h6.y;  bx += h7.x; by += h7.y;
        }
        for (; j + 4 <= cnt; j += 4) {
            int i0 = __shfl(myidx, j,     64);
            int i1 = __shfl(myidx, j + 1, 64);
            int i2 = __shfl(myidx, j + 2, 64);
            int i3 = __shfl(myidx, j + 3, 64);
            float2 h0 = hp2[(size_t)i0 * 64 + lane];
            float2 h1 = hp2[(size_t)i1 * 64 + lane];
            float2 h2 = hp2[(size_t)i2 * 64 + lane];
            float2 h3 = hp2[(size_t)i3 * 64 + lane];
            ax += h0.x; ay += h0.y;  bx += h1.x; by += h1.y;
            ax += h2.x; ay += h2.y;  bx += h3.x; by += h3.y;
        }
        for (; j < cnt; ++j) {
            int s = __shfl(myidx, j, 64);
            float2 hv = hp2[(size_t)s * 64 + lane];
            ax += hv.x; ay += hv.y;
        }
    }

    float dv = dinv[v];
    float2 bb = *reinterpret_cast<const float2*>(&bias[lane * 2]);
    float ox = dv * (ax + bx) + bb.x;
    float oy = dv * (ay + by) + bb.y;
    if (do_relu) { ox = fmaxf(ox, 0.0f); oy = fmaxf(oy, 0.0f); }

    if (PACKED) {
        // features k0=2*lane, k1=2*lane+1 of next layer's K=128 packed A;
        // tile = 4096 shorts (2048 hi + 2048 lo), fully owned by this block.
        unsigned h0 = bf16_rne(ox);
        unsigned l0 = bf16_rne(ox - __uint_as_float(h0 << 16));
        unsigned h1 = bf16_rne(oy);
        unsigned l1 = bf16_rne(oy - __uint_as_float(h1 << 16));
        int g = v >> 4, r = v & 15;
        size_t a = (size_t)g * 4096 + (lane >> 2) * 128 + r * 8 + ((2 * lane) & 7);
        *reinterpret_cast<short2*>(&Axp[a])        = make_short2((short)h0, (short)h1);
        *reinterpret_cast<short2*>(&Axp[a + 2048]) = make_short2((short)l0, (short)l1);
    } else {
        *reinterpret_cast<float2*>(&outf[(size_t)v * 128 + lane * 2]) = make_float2(ox, oy);
    }
}

// ---------------- decode: 32 lanes per edge, float4 per lane ----------------

__global__ __launch_bounds__(256) void decode_kernel(const int* __restrict__ ia,
                                                     const int* __restrict__ ib,
                                                     const float* __restrict__ z,
                                                     float* __restrict__ out, int EL) {
    int gid = blockIdx.x * blockDim.x + threadIdx.x;
    int e = gid >> 5;
    int l5 = gid & 31;
    if (e >= EL) return;
    int a = ia[e], b = ib[e];
    const float4* z4 = reinterpret_cast<const float4*>(z);
    float4 za = z4[(size_t)a * 32 + l5];
    float4 zb = z4[(size_t)b * 32 + l5];
    float s = za.x * zb.x + za.y * zb.y + za.z * zb.z + za.w * zb.w;
#pragma unroll
    for (int off = 16; off > 0; off >>= 1) s += __shfl_down(s, off, 64);
    if (l5 == 0) out[e] = s;
}

// ---------------- host launch ----------------

extern "C" void kernel_launch(void* const* d_in, const int* in_sizes, int n_in,
                              void* d_out, int out_size, void* d_ws, size_t ws_size,
                              hipStream_t stream) {
    const float* x   = (const float*)d_in[0];
    const int*   ei  = (const int*)d_in[1];
    const int*   eli = (const int*)d_in[2];
    const float* W0  = (const float*)d_in[3];
    const float* b0  = (const float*)d_in[4];
    const float* W1  = (const float*)d_in[5];
    const float* b1  = (const float*)d_in[6];
    const float* W2  = (const float*)d_in[7];
    const float* b2  = (const float*)d_in[8];
    float* out = (float*)d_out;

    const int H    = in_sizes[4];            // 128
    const int F_in = in_sizes[3] / H;        // 256
    const int n    = in_sizes[0] / F_in;     // 50000
    const int E    = in_sizes[1] / 2;        // 320000
    const int EL   = in_sizes[2] / 2;        // 200000

    const int* src = ei;
    const int* dst = ei + E;
    const int* la  = eli;
    const int* lb  = eli + EL;

    const int ntiles = (n + 15) / 16;

    char* ws = (char*)d_ws;
    size_t p = 0;
    auto alloc = [&](size_t bytes) { char* r = ws + p; p = (p + bytes + 255) & ~(size_t)255; return r; };
    float* dinv    = (float*)alloc((size_t)n * 4);
    int*   off     = (int*)  alloc((size_t)n * 4);
    int*   csr_src = (int*)  alloc((size_t)E * 4);
    int*   sums    = (int*)  alloc(64 * 4);
    short* W0h     = (short*)alloc((size_t)F_in * H * 2);
    short* W0l     = (short*)alloc((size_t)F_in * H * 2);
    short* W1h     = (short*)alloc((size_t)H * H * 2);
    short* W1l     = (short*)alloc((size_t)H * H * 2);
    short* W2h     = (short*)alloc((size_t)H * H * 2);
    short* W2l     = (short*)alloc((size_t)H * H * 2);
    short* Axp     = (short*)alloc((size_t)ntiles * 16 * F_in * 2 * 2);  // interleaved hi/lo
    float* bufA    = (float*)alloc((size_t)n * 128 * 4);
    float* bufB    = (float*)alloc((size_t)n * 128 * 4);
    int*   fill    = (int*)bufB;   // alias: only used during CSR build

    const int T = 256;
    dim3 blk(T);

    // ---- fused preamble: zero off/fill + split all W + pack x
    {
        int n0 = F_in * H, n12 = H * H;
        long long total = (long long)n + n0 + 2 * n12 + (long long)ntiles * 16 * (F_in / 8);
        preamble_kernel<<<(int)((total + T - 1) / T), blk, 0, stream>>>(
            W0, W0h, W0l, W1, W1h, W1l, W2, W2h, W2l, x, Axp, off, fill,
            n, F_in, H, ntiles, (int)total);
    }
    count_deg_kernel<<<(E + T - 1) / T, blk, 0, stream>>>(dst, off, E);
    int nb = (n + 1023) / 1024;
    scan1_kernel<<<nb, 1024, 0, stream>>>(off, sums, n);
    scan2_kernel<<<1, 64, 0, stream>>>(sums, nb);
    scan3_kernel<<<nb, 1024, 0, stream>>>(off, sums, n);
    make_dinv_kernel<<<(n + T - 1) / T, blk, 0, stream>>>(off, dinv, n, E);
    csr_fill_kernel<<<(E + T - 1) / T, blk, 0, stream>>>(src, dst, off, fill, csr_src, E);

    const int mblocks       = (ntiles + 1) / 2;      // 2 tiles per block (2 waves/tile)
    const int gather_blocks = (n + 15) / 16;         // 16 nodes (waves) per 1024-thr block

    // ---- layer 0: x(256) -> 128, relu; gather writes packed A for layer 1
    gemm_mfma_packed<256><<<mblocks, blk, 0, stream>>>(Axp, W0h, W0l, dinv, bufA, n);
    gather_kernel<1><<<gather_blocks, 1024, 0, stream>>>(off, csr_src, dinv, bufA, b0,
                                                         nullptr, Axp, n, E, 1);

    // ---- layer 1: 128 -> 128, relu; gather writes packed A for layer 2
    gemm_mfma_packed<128><<<mblocks, blk, 0, stream>>>(Axp, W1h, W1l, dinv, bufA, n);
    gather_kernel<1><<<gather_blocks, 1024, 0, stream>>>(off, csr_src, dinv, bufA, b1,
                                                         nullptr, Axp, n, E, 1);

    // ---- layer 2: 128 -> 128, no activation; gather writes fp32 z rows
    gemm_mfma_packed<128><<<mblocks, blk, 0, stream>>>(Axp, W2h, W2l, dinv, bufA, n);
    gather_kernel<0><<<gather_blocks, 1024, 0, stream>>>(off, csr_src, dinv, bufA, b2,
                                                         bufB, nullptr, n, E, 0);

    // ---- decode
    const int dec_blocks = (int)(((long long)EL * 32 + T - 1) / T);
    decode_kernel<<<dec_blocks, blk, 0, stream>>>(la, lb, bufB, out, EL);
}

// Round 14
// 322.134 us; speedup vs baseline: 1.2508x; 1.0300x over previous
//
#include <hip/hip_runtime.h>
#include <hip/hip_bf16.h>

// ---------------------------------------------------------------------------
// GCN edge prediction.
//   Packed MFMA-fragment operands (tile = 16 rows: hi[16*K] then lo[16*K],
//   elem(r,k) at (k/8)*128 + r*8 + k%8). Gather: 2 nodes/wave (32-lane
//   groups, float4/lane) for 2x memory-level parallelism; dinv recomputed
//   from CSR offsets (no dinv array, no make_dinv dispatch); scan3
//   self-reduces block sums (no scan2 dispatch). 11 dispatches total.
// ---------------------------------------------------------------------------

typedef __attribute__((ext_vector_type(8))) short short8v;   // 8 bf16 = 4 VGPR
typedef __attribute__((ext_vector_type(4))) short short4v;   // 4 bf16
typedef __attribute__((ext_vector_type(4))) float f32x4;

__device__ inline unsigned bf16_rne(float f) {
    unsigned u = __float_as_uint(f);
    return (u + 0x7FFF + ((u >> 16) & 1)) >> 16;   // round-to-nearest-even
}

// ---------------- fused preamble: zero CSR arrays + split W + pack x ---------

__device__ inline void split_pack_one(const float* W, short* Whp, short* Wlp,
                                      int idx, int K) {
    int k = idx >> 7, col = idx & 127;
    float f = W[idx];
    unsigned h = bf16_rne(f);
    float fh = __uint_as_float(h << 16);
    unsigned l = bf16_rne(f - fh);
    int NS = K >> 5;
    int c = col >> 4, col16 = col & 15, s = k >> 5, q = (k >> 3) & 3, j = k & 7;
    int waddr = (c * NS + s) * 512 + q * 128 + col16 * 8 + j;
    Whp[waddr] = (short)h;
    Wlp[waddr] = (short)l;
}

__global__ __launch_bounds__(256) void preamble_kernel(
        const float* __restrict__ W0, short* __restrict__ W0h, short* __restrict__ W0l,
        const float* __restrict__ W1, short* __restrict__ W1h, short* __restrict__ W1l,
        const float* __restrict__ W2, short* __restrict__ W2h, short* __restrict__ W2l,
        const float* __restrict__ x, short* __restrict__ Axp,
        int* __restrict__ off, int* __restrict__ fill,
        int n, int F_in, int H, int ntiles, int total) {
    int gid = blockIdx.x * blockDim.x + threadIdx.x;
    if (gid >= total) return;
    int idx = gid;
    if (idx < n) { off[idx] = 0; fill[idx] = 0; return; }
    idx -= n;
    int n0 = F_in * H, n12 = H * H;
    if (idx < n0) { split_pack_one(W0, W0h, W0l, idx, F_in); return; }
    idx -= n0;
    if (idx < n12) { split_pack_one(W1, W1h, W1l, idx, H); return; }
    idx -= n12;
    if (idx < n12) { split_pack_one(W2, W2h, W2l, idx, H); return; }
    idx -= n12;
    // pack x (K = F_in)
    const int K = F_in;
    const int CH = K / 8;
    int r  = idx & 15;
    int c8 = (idx >> 4) % CH;
    int g  = idx / (16 * CH);
    int row = g * 16 + r;
    if (row >= n) row = n - 1;                      // clamp (pad tiles)
    const float* xp = x + (size_t)row * K + c8 * 8;
    float4 v0 = *reinterpret_cast<const float4*>(xp);
    float4 v1 = *reinterpret_cast<const float4*>(xp + 4);
    float f[8] = {v0.x, v0.y, v0.z, v0.w, v1.x, v1.y, v1.z, v1.w};
    short8v hv, lv;
#pragma unroll
    for (int j = 0; j < 8; ++j) {
        unsigned h = bf16_rne(f[j]);
        float fh = __uint_as_float(h << 16);
        unsigned l = bf16_rne(f[j] - fh);
        hv[j] = (short)h;
        lv[j] = (short)l;
    }
    size_t base = (size_t)g * (16 * K * 2) + c8 * 128 + r * 8;
    *reinterpret_cast<short8v*>(&Axp[base]) = hv;
    *reinterpret_cast<short8v*>(&Axp[base + 16 * K]) = lv;
}

// ---------------- CSR build ----------------

__global__ void count_deg_kernel(const int* __restrict__ dst, int* __restrict__ deg, int E) {
    int e = blockIdx.x * blockDim.x + threadIdx.x;
    if (e < E) atomicAdd(&deg[dst[e]], 1);
}

__global__ __launch_bounds__(1024) void scan1_kernel(int* __restrict__ data,
                                                     int* __restrict__ sums, int n) {
    __shared__ int tmp[1024];
    int t = threadIdx.x;
    int idx = blockIdx.x * 1024 + t;
    int val = (idx < n) ? data[idx] : 0;
    tmp[t] = val;
    __syncthreads();
#pragma unroll
    for (int off = 1; off < 1024; off <<= 1) {
        int v = (t >= off) ? tmp[t - off] : 0;
        __syncthreads();
        tmp[t] += v;
        __syncthreads();
    }
    if (idx < n) data[idx] = tmp[t] - val;
    if (t == 1023) sums[blockIdx.x] = tmp[t];
}

// scan3 self-reduces block sums (nb <= 64): thread 0 sums predecessors.
__global__ __launch_bounds__(1024) void scan3_kernel(int* __restrict__ data,
                                                     const int* __restrict__ sums, int n) {
    __shared__ int base;
    if (threadIdx.x == 0) {
        int s = 0;
        for (int b = 0; b < blockIdx.x; ++b) s += sums[b];
        base = s;
    }
    __syncthreads();
    int idx = blockIdx.x * 1024 + threadIdx.x;
    if (idx < n && blockIdx.x > 0) data[idx] += base;
}

__global__ void csr_fill_kernel(const int* __restrict__ src, const int* __restrict__ dst,
                                const int* __restrict__ off, int* __restrict__ fill,
                                int* __restrict__ csr_src, int E) {
    int e = blockIdx.x * blockDim.x + threadIdx.x;
    if (e >= E) return;
    int d = dst[e];
    int pos = atomicAdd(&fill[d], 1);
    csr_src[off[d] + pos] = src[e];
}

// ---------------- packed-operand MFMA GEMM ----------------
// out[M][128] = dinv[row]*(A @ W); dinv recomputed from off. 256 thr = 4 waves;
// 2 waves per 16-row tile, each wave owns 4 of 8 col-blocks.

template<int K>
__global__ __launch_bounds__(256) void gemm_mfma_packed(const short* __restrict__ Axp,
                                                        const short* __restrict__ Whp,
                                                        const short* __restrict__ Wlp,
                                                        const int* __restrict__ off,
                                                        float* __restrict__ out,
                                                        int M, int E) {
    constexpr int NS = K / 32;
    constexpr size_t TILE = (size_t)16 * K * 2;
    const int lane = threadIdx.x & 63;
    const int w = threadIdx.x >> 6;
    const int gtile = blockIdx.x * 2 + (w >> 1);
    const int chalf = (w & 1) * 4;
    const int row16 = gtile * 16;
    if (row16 >= M) return;

    const short* ab = Axp + (size_t)gtile * TILE + lane * 8;
    const short* lb = ab + 16 * K;

    short8v ah[NS], al[NS];
#pragma unroll
    for (int s = 0; s < NS; ++s) {
        ah[s] = *reinterpret_cast<const short8v*>(ab + s * 512);
        al[s] = *reinterpret_cast<const short8v*>(lb + s * 512);
    }

    f32x4 acc[4];
#pragma unroll
    for (int c = 0; c < 4; ++c) acc[c] = (f32x4){0.f, 0.f, 0.f, 0.f};

#pragma unroll
    for (int c4 = 0; c4 < 4; ++c4) {
        int c = chalf + c4;
        const short* bb = Whp + (size_t)(c * NS) * 512 + lane * 8;
        const short* cb = Wlp + (size_t)(c * NS) * 512 + lane * 8;
#pragma unroll
        for (int s = 0; s < NS; ++s) {
            short8v bh = *reinterpret_cast<const short8v*>(bb + s * 512);
            short8v bl = *reinterpret_cast<const short8v*>(cb + s * 512);
            acc[c4] = __builtin_amdgcn_mfma_f32_16x16x32_bf16(ah[s], bh, acc[c4], 0, 0, 0);
            acc[c4] = __builtin_amdgcn_mfma_f32_16x16x32_bf16(ah[s], bl, acc[c4], 0, 0, 0);
            acc[c4] = __builtin_amdgcn_mfma_f32_16x16x32_bf16(al[s], bh, acc[c4], 0, 0, 0);
        }
    }

    // epilogue: dinv[row] = 1/sqrt(indeg+1) from off; C/D col=lane&15, row=(lane>>4)*4+r
#pragma unroll
    for (int r = 0; r < 4; ++r) {
        int row = row16 + (lane >> 4) * 4 + r;
        if (row < M) {
            int o0 = off[row];
            int o1 = (row + 1 < M) ? off[row + 1] : E;
            float ds = 1.0f / sqrtf((float)(o1 - o0) + 1.0f);
#pragma unroll
            for (int c4 = 0; c4 < 4; ++c4)
                out[(size_t)row * 128 + (chalf + c4) * 16 + (lane & 15)] = acc[c4][r] * ds;
        }
    }
}

// ---------------- gather ----------------
// out[v] = relu( dv*(sum_{s in N(v)} h'[s] + h'[v]) + bias ), h' = dinv*h.
// 2 nodes per wave: 32-lane groups, float4 per lane (one dwordx4 = full 512B
// row per group) -> 2x independent load streams per wave.
// 1024-thr block = 32 consecutive nodes = 2 full packed tiles (block-owned).

template<int PACKED>
__global__ __launch_bounds__(1024) void gather_kernel(const int* __restrict__ off,
                                                      const int* __restrict__ csr_src,
                                                      const float* __restrict__ hp,
                                                      const float* __restrict__ bias,
                                                      float* __restrict__ outf,
                                                      short* __restrict__ Axp,
                                                      int n, int E, int do_relu) {
    int v = blockIdx.x * 32 + (threadIdx.x >> 5);
    int l5 = threadIdx.x & 31;
    if (v >= n) return;

    int o0 = off[v];
    int o1 = (v + 1 < n) ? off[v + 1] : E;
    float dv = 1.0f / sqrtf((float)(o1 - o0) + 1.0f);

    const float4* __restrict__ hp4 = reinterpret_cast<const float4*>(hp);
    float4 sv = hp4[(size_t)v * 32 + l5];            // self row
    float ax = sv.x, ay = sv.y, az = sv.z, aw = sv.w;
    float bx = 0.f, by = 0.f, bz = 0.f, bw = 0.f;

    for (int base = o0; base < o1; base += 32) {
        int cnt = min(32, o1 - base);
        int myidx = (l5 < cnt) ? csr_src[base + l5] : 0;
        int j = 0;
        for (; j + 4 <= cnt; j += 4) {
            int i0 = __shfl(myidx, j,     32);
            int i1 = __shfl(myidx, j + 1, 32);
            int i2 = __shfl(myidx, j + 2, 32);
            int i3 = __shfl(myidx, j + 3, 32);
            float4 h0 = hp4[(size_t)i0 * 32 + l5];
            float4 h1 = hp4[(size_t)i1 * 32 + l5];
            float4 h2 = hp4[(size_t)i2 * 32 + l5];
            float4 h3 = hp4[(size_t)i3 * 32 + l5];
            ax += h0.x; ay += h0.y; az += h0.z; aw += h0.w;
            bx += h1.x; by += h1.y; bz += h1.z; bw += h1.w;
            ax += h2.x; ay += h2.y; az += h2.z; aw += h2.w;
            bx += h3.x; by += h3.y; bz += h3.z; bw += h3.w;
        }
        for (; j < cnt; ++j) {
            int s = __shfl(myidx, j, 32);
            float4 hv = hp4[(size_t)s * 32 + l5];
            ax += hv.x; ay += hv.y; az += hv.z; aw += hv.w;
        }
    }

    float4 bb = reinterpret_cast<const float4*>(bias)[l5];
    float ox = dv * (ax + bx) + bb.x;
    float oy = dv * (ay + by) + bb.y;
    float oz = dv * (az + bz) + bb.z;
    float ow = dv * (aw + bw) + bb.w;
    if (do_relu) {
        ox = fmaxf(ox, 0.0f); oy = fmaxf(oy, 0.0f);
        oz = fmaxf(oz, 0.0f); ow = fmaxf(ow, 0.0f);
    }

    if (PACKED) {
        // features k = 4*l5 .. 4*l5+3 of next layer's K=128 packed A;
        // tile = 4096 shorts (2048 hi + 2048 lo), block-owned.
        float f[4] = {ox, oy, oz, ow};
        short4v hv, lv;
#pragma unroll
        for (int j = 0; j < 4; ++j) {
            unsigned h = bf16_rne(f[j]);
            float fh = __uint_as_float(h << 16);
            unsigned l = bf16_rne(f[j] - fh);
            hv[j] = (short)h;
            lv[j] = (short)l;
        }
        int g = v >> 4, r = v & 15;
        size_t a = (size_t)g * 4096 + (l5 >> 1) * 128 + r * 8 + (l5 & 1) * 4;
        *reinterpret_cast<short4v*>(&Axp[a])        = hv;
        *reinterpret_cast<short4v*>(&Axp[a + 2048]) = lv;
    } else {
        float4 ov = make_float4(ox, oy, oz, ow);
        reinterpret_cast<float4*>(outf)[(size_t)v * 32 + l5] = ov;
    }
}

// ---------------- decode: 32 lanes per edge, float4 per lane ----------------

__global__ __launch_bounds__(256) void decode_kernel(const int* __restrict__ ia,
                                                     const int* __restrict__ ib,
                                                     const float* __restrict__ z,
                                                     float* __restrict__ out, int EL) {
    int gid = blockIdx.x * blockDim.x + threadIdx.x;
    int e = gid >> 5;
    int l5 = gid & 31;
    if (e >= EL) return;
    int a = ia[e], b = ib[e];
    const float4* z4 = reinterpret_cast<const float4*>(z);
    float4 za = z4[(size_t)a * 32 + l5];
    float4 zb = z4[(size_t)b * 32 + l5];
    float s = za.x * zb.x + za.y * zb.y + za.z * zb.z + za.w * zb.w;
#pragma unroll
    for (int off = 16; off > 0; off >>= 1) s += __shfl_down(s, off, 64);
    if (l5 == 0) out[e] = s;
}

// ---------------- host launch ----------------

extern "C" void kernel_launch(void* const* d_in, const int* in_sizes, int n_in,
                              void* d_out, int out_size, void* d_ws, size_t ws_size,
                              hipStream_t stream) {
    const float* x   = (const float*)d_in[0];
    const int*   ei  = (const int*)d_in[1];
    const int*   eli = (const int*)d_in[2];
    const float* W0  = (const float*)d_in[3];
    const float* b0  = (const float*)d_in[4];
    const float* W1  = (const float*)d_in[5];
    const float* b1  = (const float*)d_in[6];
    const float* W2  = (const float*)d_in[7];
    const float* b2  = (const float*)d_in[8];
    float* out = (float*)d_out;

    const int H    = in_sizes[4];            // 128
    const int F_in = in_sizes[3] / H;        // 256
    const int n    = in_sizes[0] / F_in;     // 50000
    const int E    = in_sizes[1] / 2;        // 320000
    const int EL   = in_sizes[2] / 2;        // 200000

    const int* src = ei;
    const int* dst = ei + E;
    const int* la  = eli;
    const int* lb  = eli + EL;

    const int ntiles = (n + 15) / 16;

    char* ws = (char*)d_ws;
    size_t p = 0;
    auto alloc = [&](size_t bytes) { char* r = ws + p; p = (p + bytes + 255) & ~(size_t)255; return r; };
    int*   off     = (int*)  alloc((size_t)n * 4);
    int*   csr_src = (int*)  alloc((size_t)E * 4);
    int*   sums    = (int*)  alloc(64 * 4);
    short* W0h     = (short*)alloc((size_t)F_in * H * 2);
    short* W0l     = (short*)alloc((size_t)F_in * H * 2);
    short* W1h     = (short*)alloc((size_t)H * H * 2);
    short* W1l     = (short*)alloc((size_t)H * H * 2);
    short* W2h     = (short*)alloc((size_t)H * H * 2);
    short* W2l     = (short*)alloc((size_t)H * H * 2);
    short* Axp     = (short*)alloc((size_t)ntiles * 16 * F_in * 2 * 2);  // interleaved hi/lo
    float* bufA    = (float*)alloc((size_t)n * 128 * 4);
    float* bufB    = (float*)alloc((size_t)n * 128 * 4);
    int*   fill    = (int*)bufB;   // alias: only used during CSR build

    const int T = 256;
    dim3 blk(T);

    // ---- fused preamble: zero off/fill + split all W + pack x
    {
        int n0 = F_in * H, n12 = H * H;
        long long total = (long long)n + n0 + 2 * n12 + (long long)ntiles * 16 * (F_in / 8);
        preamble_kernel<<<(int)((total + T - 1) / T), blk, 0, stream>>>(
            W0, W0h, W0l, W1, W1h, W1l, W2, W2h, W2l, x, Axp, off, fill,
            n, F_in, H, ntiles, (int)total);
    }
    count_deg_kernel<<<(E + T - 1) / T, blk, 0, stream>>>(dst, off, E);
    int nb = (n + 1023) / 1024;
    scan1_kernel<<<nb, 1024, 0, stream>>>(off, sums, n);
    scan3_kernel<<<nb, 1024, 0, stream>>>(off, sums, n);
    csr_fill_kernel<<<(E + T - 1) / T, blk, 0, stream>>>(src, dst, off, fill, csr_src, E);

    const int mblocks       = (ntiles + 1) / 2;      // 2 tiles per block
    const int gather_blocks = (n + 31) / 32;         // 32 nodes per 1024-thr block

    // ---- layer 0: x(256) -> 128, relu; gather writes packed A for layer 1
    gemm_mfma_packed<256><<<mblocks, blk, 0, stream>>>(Axp, W0h, W0l, off, bufA, n, E);
    gather_kernel<1><<<gather_blocks, 1024, 0, stream>>>(off, csr_src, bufA, b0,
                                                         nullptr, Axp, n, E, 1);

    // ---- layer 1: 128 -> 128, relu; gather writes packed A for layer 2
    gemm_mfma_packed<128><<<mblocks, blk, 0, stream>>>(Axp, W1h, W1l, off, bufA, n, E);
    gather_kernel<1><<<gather_blocks, 1024, 0, stream>>>(off, csr_src, bufA, b1,
                                                         nullptr, Axp, n, E, 1);

    // ---- layer 2: 128 -> 128, no activation; gather writes fp32 z rows
    gemm_mfma_packed<128><<<mblocks, blk, 0, stream>>>(Axp, W2h, W2l, off, bufA, n, E);
    gather_kernel<0><<<gather_blocks, 1024, 0, stream>>>(off, csr_src, bufA, b2,
                                                         bufB, nullptr, n, E, 0);

    // ---- decode
    const int dec_blocks = (int)(((long long)EL * 32 + T - 1) / T);
    decode_kernel<<<dec_blocks, blk, 0, stream>>>(la, lb, bufB, out, EL);
}